// Round 14
// baseline (80700.598 us; speedup 1.0000x reference)
//
#include <hip/hip_runtime.h>

typedef __bf16 bf16x8 __attribute__((ext_vector_type(8)));
typedef float f32x4 __attribute__((ext_vector_type(4)));
typedef unsigned u32x4 __attribute__((ext_vector_type(4)));

#define HID 512
#define BATCH 1024
#define SEQL 512
#define NWG 64
#define NTHR 1024

// ---- workspace: weight hi/lo planes only (no exchange buffers, no barriers) ----
#define OFF_ENH 0u          // enc_whh hi : 1536*512*2
#define OFF_ENL 1572864u
#define OFF_DEH 3145728u
#define OFF_DEL 4718592u
#define OFF_W1H 6291456u    // w1 hi : 512*512*2
#define OFF_W1L 6815744u
#define WS_NEED 7340032u

// LDS: packed h (bf16 hi | lo<<16) u32 [16][512], XOR-swizzled (32 KB),
// + y-partials [16 rows][16 waves] f32 @32768 (1KB) + y[16] @33792 (64B).
#define LDS_PS 32768
#define LDS_Y 33792
#define SWZP(row, cb) (((row) << 11) + ((cb) ^ (((row) & 7) << 4)))

__device__ __forceinline__ f32x4 mfma16(bf16x8 a, bf16x8 b, f32x4 c) {
  return __builtin_amdgcn_mfma_f32_16x16x32_bf16(a, b, c, 0, 0, 0);
}
__device__ __forceinline__ float sig_(float x) { return 1.0f / (1.0f + __expf(-x)); }
__device__ __forceinline__ float tanh_(float x) { return 1.0f - 2.0f / (__expf(2.0f * x) + 1.0f); }

__global__ void split_w(const float* __restrict__ a, __bf16* __restrict__ hi,
                        __bf16* __restrict__ lo, int n) {
  int i = blockIdx.x * blockDim.x + threadIdx.x;
  if (i < n) {
    float v = a[i];
    __bf16 h = (__bf16)v;
    hi[i] = h;
    lo[i] = (__bf16)(v - (float)h);
  }
}

// Read one MFMA A-fragment (16 rows x 32 k, this lane's 8 k-elements) from the
// packed-u32 LDS plane and unpack to hi/lo bf16x8. cb = byte col offset.
__device__ __forceinline__ void rd_afrag(const char* sm, int lan15, int cb, bf16x8& ah,
                                         bf16x8& al) {
  const u32x4 q0 = *(const u32x4*)(sm + SWZP(lan15, cb));
  const u32x4 q1 = *(const u32x4*)(sm + SWZP(lan15, cb + 16));
  u32x4 h, l;
  h.x = (q0.x & 0xffffu) | (q0.y << 16);
  h.y = (q0.z & 0xffffu) | (q0.w << 16);
  h.z = (q1.x & 0xffffu) | (q1.y << 16);
  h.w = (q1.z & 0xffffu) | (q1.w << 16);
  l.x = (q0.x >> 16) | (q0.y & 0xffff0000u);
  l.y = (q0.z >> 16) | (q0.w & 0xffff0000u);
  l.z = (q1.x >> 16) | (q1.y & 0xffff0000u);
  l.w = (q1.z >> 16) | (q1.w & 0xffff0000u);
  ah = __builtin_bit_cast(bf16x8, h);
  al = __builtin_bit_cast(bf16x8, l);
}

// WG = 16 batch rows x ALL 512 hidden cols: the whole recurrence is WG-local.
// 16 waves (4/SIMD); wave wv owns hidden cols [32*wv, 32*wv+32) (2 frags x 3 gates).
// Per kc: 12 B-loads (48 VGPRs) -> fits the budget, issues as ONE batch.
__global__ void __launch_bounds__(NTHR, 1) seq2seq_main(
    const float* __restrict__ src, const float* __restrict__ enc_wih,
    const float* __restrict__ enc_bih, const float* __restrict__ enc_bhh,
    const float* __restrict__ dec_wih, const float* __restrict__ dec_bih,
    const float* __restrict__ dec_bhh, const float* __restrict__ b1,
    const float* __restrict__ w2, const float* __restrict__ b2,
    const int* __restrict__ hor, float* __restrict__ out, char* __restrict__ ws) {
  __shared__ f32x4 smv[2116];  // 33856 B
  char* sm = (char*)smv;
  float* psum = (float*)(sm + LDS_PS);
  float* ylds = (float*)(sm + LDS_Y);

  const __bf16* ench_hi = (const __bf16*)(ws + OFF_ENH);
  const __bf16* ench_lo = (const __bf16*)(ws + OFF_ENL);
  const __bf16* dech_hi = (const __bf16*)(ws + OFF_DEH);
  const __bf16* dech_lo = (const __bf16*)(ws + OFF_DEL);
  const __bf16* w1h = (const __bf16*)(ws + OFF_W1H);
  const __bf16* w1l = (const __bf16*)(ws + OFF_W1L);

  const int G = blockIdx.x;  // rows [16G, 16G+16)
  const int row0 = G << 4;
  const int tid = threadIdx.x;
  const int wv = tid >> 6;   // 0..15
  const int lane = tid & 63;
  const int lan15 = lane & 15;
  const int l4 = lane >> 4;
  const int kbe = l4 << 3;  // A/B k-offset (elements) within 32-chunk

  // B element offsets: gate g, col frag nf -> B row (g*512 + c), c = wv*32+nf*16+lan15
  int boff[3][2];
#pragma unroll
  for (int g = 0; g < 3; ++g)
#pragma unroll
    for (int nf = 0; nf < 2; ++nf)
      boff[g][nf] = (((g << 9) + (wv << 5) + (nf << 4) + lan15) << 9) + kbe;
  int bofffc[2];
#pragma unroll
  for (int nf = 0; nf < 2; ++nf) bofffc[nf] = (((wv << 5) + (nf << 4) + lan15) << 9) + kbe;

  // hoisted encoder gate params (input matmul K=3 inline, f32)
  float wE[3][2][3], biE[3][2], bhE[3][2];
#pragma unroll
  for (int g = 0; g < 3; ++g)
#pragma unroll
    for (int nf = 0; nf < 2; ++nf) {
      const int j = (g << 9) + (wv << 5) + (nf << 4) + lan15;
      wE[g][nf][0] = enc_wih[j * 3 + 0];
      wE[g][nf][1] = enc_wih[j * 3 + 1];
      wE[g][nf][2] = enc_wih[j * 3 + 2];
      biE[g][nf] = enc_bih[j];
      bhE[g][nf] = enc_bhh[j];
    }

  const f32x4 zf = {0.0f, 0.0f, 0.0f, 0.0f};
  float hpv[2][4];  // [nf][reg] f32 carry of h for this lane's outputs
#pragma unroll
  for (int nf = 0; nf < 2; ++nf)
#pragma unroll
    for (int reg = 0; reg < 4; ++reg) hpv[nf][reg] = 0.0f;

  // ================= encoder: 512 steps, fully WG-local =================
  for (int t = 0; t < SEQL; ++t) {
    float xv[4][3];
#pragma unroll
    for (int reg = 0; reg < 4; ++reg) {
      const int grow = row0 + (l4 << 2) + reg;
      const float* xp = src + ((size_t)t * BATCH + grow) * 3;
      xv[reg][0] = xp[0];
      xv[reg][1] = xp[1];
      xv[reg][2] = xp[2];
    }

    f32x4 acc[3][2];
#pragma unroll
    for (int g = 0; g < 3; ++g)
#pragma unroll
      for (int nf = 0; nf < 2; ++nf) acc[g][nf] = zf;

    if (t != 0) {
#pragma unroll
      for (int kc = 0; kc < 16; ++kc) {
        const int ko = kc << 5;
        // one batch of 12 global loads first (fits regs -> single issue group)
        bf16x8 bh[3][2], bl[3][2];
#pragma unroll
        for (int g = 0; g < 3; ++g)
#pragma unroll
          for (int nf = 0; nf < 2; ++nf) {
            bh[g][nf] = *(const bf16x8*)(ench_hi + boff[g][nf] + ko);
            bl[g][nf] = *(const bf16x8*)(ench_lo + boff[g][nf] + ko);
          }
        bf16x8 ah, al;
        rd_afrag(sm, lan15, (kc << 7) + (l4 << 5), ah, al);
#pragma unroll
        for (int g = 0; g < 3; ++g)
#pragma unroll
          for (int nf = 0; nf < 2; ++nf) {
            acc[g][nf] = mfma16(ah, bh[g][nf], acc[g][nf]);
            acc[g][nf] = mfma16(al, bh[g][nf], acc[g][nf]);
            acc[g][nf] = mfma16(ah, bl[g][nf], acc[g][nf]);
          }
      }
    }
    __syncthreads();  // all h_t reads done before overwrite

#pragma unroll
    for (int reg = 0; reg < 4; ++reg) {
      const int row = (l4 << 2) + reg;
      const float x0 = xv[reg][0], x1 = xv[reg][1], x2 = xv[reg][2];
#pragma unroll
      for (int nf = 0; nf < 2; ++nf) {
        const float gir =
            fmaf(x0, wE[0][nf][0], fmaf(x1, wE[0][nf][1], fmaf(x2, wE[0][nf][2], biE[0][nf])));
        const float giz =
            fmaf(x0, wE[1][nf][0], fmaf(x1, wE[1][nf][1], fmaf(x2, wE[1][nf][2], biE[1][nf])));
        const float gin =
            fmaf(x0, wE[2][nf][0], fmaf(x1, wE[2][nf][1], fmaf(x2, wE[2][nf][2], biE[2][nf])));
        const float rg = sig_(gir + acc[0][nf][reg] + bhE[0][nf]);
        const float zg = sig_(giz + acc[1][nf][reg] + bhE[1][nf]);
        const float ng = tanh_(gin + rg * (acc[2][nf][reg] + bhE[2][nf]));
        const float hv = fmaf(zg, hpv[nf][reg] - ng, ng);  // (1-z)*n + z*h
        hpv[nf][reg] = hv;
        const __bf16 hb = (__bf16)hv;
        const __bf16 lb = (__bf16)(hv - (float)hb);
        const unsigned pw = (unsigned)__builtin_bit_cast(unsigned short, hb) |
                            ((unsigned)__builtin_bit_cast(unsigned short, lb) << 16);
        const int col = (wv << 5) + (nf << 4) + lan15;
        *(unsigned*)(sm + SWZP(row, col << 2)) = pw;
      }
    }
    __syncthreads();  // h_{t+1} visible to all waves
  }

  // ================= decoder: fully WG-local =================
  float wD[3][2], biD[3][2], bhD[3][2], b1c[2], w2v[2];
#pragma unroll
  for (int g = 0; g < 3; ++g)
#pragma unroll
    for (int nf = 0; nf < 2; ++nf) {
      const int j = (g << 9) + (wv << 5) + (nf << 4) + lan15;
      wD[g][nf] = dec_wih[j];
      biD[g][nf] = dec_bih[j];
      bhD[g][nf] = dec_bhh[j];
    }
#pragma unroll
  for (int nf = 0; nf < 2; ++nf) {
    const int fcol = (wv << 5) + (nf << 4) + lan15;
    b1c[nf] = b1[fcol];
    w2v[nf] = w2[fcol];
  }
  const float b2v = b2[0];
  int H = hor[0];
  if (H < 1 || H > 96) H = 96;

  float facc[2][4];  // fc1 (relu'd, biased), lives across step boundary

  for (int t = 0; t < H; ++t) {
    // ---- y(t-1) feedback via LDS partial reduce ----
    float din[4];
    if (t == 0) {
#pragma unroll
      for (int reg = 0; reg < 4; ++reg)
        din[reg] = src[((size_t)(SEQL - 1) * BATCH + row0 + (l4 << 2) + reg) * 3];
    } else {
      float ps[4];
#pragma unroll
      for (int reg = 0; reg < 4; ++reg) {
        ps[reg] = fmaf(facc[0][reg], w2v[0], facc[1][reg] * w2v[1]);
#pragma unroll
        for (int off = 1; off < 16; off <<= 1) ps[reg] += __shfl_xor(ps[reg], off, 64);
      }
      if (lan15 == 0) {
#pragma unroll
        for (int reg = 0; reg < 4; ++reg) psum[(((l4 << 2) + reg) << 4) + wv] = ps[reg];
      }
      __syncthreads();
      if (wv == 0 && lane < 16) {
        float s = b2v;
#pragma unroll
        for (int j = 0; j < 16; ++j) s += psum[(lane << 4) + j];
        ylds[lane] = s;
        out[(size_t)(t - 1) * BATCH + row0 + lane] = s;
      }
      __syncthreads();
#pragma unroll
      for (int reg = 0; reg < 4; ++reg) din[reg] = ylds[(l4 << 2) + reg];
    }

    // ---- gates GEMM (h_t from LDS) ----
    f32x4 acc[3][2];
#pragma unroll
    for (int g = 0; g < 3; ++g)
#pragma unroll
      for (int nf = 0; nf < 2; ++nf) acc[g][nf] = zf;
#pragma unroll
    for (int kc = 0; kc < 16; ++kc) {
      const int ko = kc << 5;
      bf16x8 bh[3][2], bl[3][2];
#pragma unroll
      for (int g = 0; g < 3; ++g)
#pragma unroll
        for (int nf = 0; nf < 2; ++nf) {
          bh[g][nf] = *(const bf16x8*)(dech_hi + boff[g][nf] + ko);
          bl[g][nf] = *(const bf16x8*)(dech_lo + boff[g][nf] + ko);
        }
      bf16x8 ah, al;
      rd_afrag(sm, lan15, (kc << 7) + (l4 << 5), ah, al);
#pragma unroll
      for (int g = 0; g < 3; ++g)
#pragma unroll
        for (int nf = 0; nf < 2; ++nf) {
          acc[g][nf] = mfma16(ah, bh[g][nf], acc[g][nf]);
          acc[g][nf] = mfma16(al, bh[g][nf], acc[g][nf]);
          acc[g][nf] = mfma16(ah, bl[g][nf], acc[g][nf]);
        }
    }
    __syncthreads();  // all h_t reads done

    // ---- epilogue: h_{t+1} -> LDS ----
#pragma unroll
    for (int reg = 0; reg < 4; ++reg) {
      const int row = (l4 << 2) + reg;
      const float d = din[reg];
#pragma unroll
      for (int nf = 0; nf < 2; ++nf) {
        const float rg = sig_(fmaf(d, wD[0][nf], biD[0][nf]) + acc[0][nf][reg] + bhD[0][nf]);
        const float zg = sig_(fmaf(d, wD[1][nf], biD[1][nf]) + acc[1][nf][reg] + bhD[1][nf]);
        const float ng =
            tanh_(fmaf(d, wD[2][nf], biD[2][nf]) + rg * (acc[2][nf][reg] + bhD[2][nf]));
        const float hv = fmaf(zg, hpv[nf][reg] - ng, ng);
        hpv[nf][reg] = hv;
        const __bf16 hb = (__bf16)hv;
        const __bf16 lb = (__bf16)(hv - (float)hb);
        const unsigned pw = (unsigned)__builtin_bit_cast(unsigned short, hb) |
                            ((unsigned)__builtin_bit_cast(unsigned short, lb) << 16);
        const int col = (wv << 5) + (nf << 4) + lan15;
        *(unsigned*)(sm + SWZP(row, col << 2)) = pw;
      }
    }
    __syncthreads();  // h_{t+1} visible

    // ---- fc1 = relu(h_{t+1} @ w1^T + b1), kept in registers ----
    f32x4 fa[2];
    fa[0] = zf;
    fa[1] = zf;
#pragma unroll
    for (int kc = 0; kc < 16; ++kc) {
      const int ko = kc << 5;
      bf16x8 bh[2], bl[2];
#pragma unroll
      for (int nf = 0; nf < 2; ++nf) {
        bh[nf] = *(const bf16x8*)(w1h + bofffc[nf] + ko);
        bl[nf] = *(const bf16x8*)(w1l + bofffc[nf] + ko);
      }
      bf16x8 ah, al;
      rd_afrag(sm, lan15, (kc << 7) + (l4 << 5), ah, al);
#pragma unroll
      for (int nf = 0; nf < 2; ++nf) {
        fa[nf] = mfma16(ah, bh[nf], fa[nf]);
        fa[nf] = mfma16(al, bh[nf], fa[nf]);
        fa[nf] = mfma16(ah, bl[nf], fa[nf]);
      }
    }
#pragma unroll
    for (int nf = 0; nf < 2; ++nf)
#pragma unroll
      for (int reg = 0; reg < 4; ++reg) facc[nf][reg] = fmaxf(fa[nf][reg] + b1c[nf], 0.0f);
  }

  // ---- final y for t = H-1 ----
  {
    float ps[4];
#pragma unroll
    for (int reg = 0; reg < 4; ++reg) {
      ps[reg] = fmaf(facc[0][reg], w2v[0], facc[1][reg] * w2v[1]);
#pragma unroll
      for (int off = 1; off < 16; off <<= 1) ps[reg] += __shfl_xor(ps[reg], off, 64);
    }
    __syncthreads();
    if (lan15 == 0) {
#pragma unroll
      for (int reg = 0; reg < 4; ++reg) psum[(((l4 << 2) + reg) << 4) + wv] = ps[reg];
    }
    __syncthreads();
    if (wv == 0 && lane < 16) {
      float s = b2v;
#pragma unroll
      for (int j = 0; j < 16; ++j) s += psum[(lane << 4) + j];
      out[(size_t)(H - 1) * BATCH + row0 + lane] = s;
    }
  }
}

extern "C" void kernel_launch(void* const* d_in, const int* in_sizes, int n_in,
                              void* d_out, int out_size, void* d_ws, size_t ws_size,
                              hipStream_t stream) {
  if (ws_size < WS_NEED) return;

  const float* src = (const float*)d_in[0];
  const float* enc_wih = (const float*)d_in[1];
  const float* enc_whh = (const float*)d_in[2];
  const float* enc_bih = (const float*)d_in[3];
  const float* enc_bhh = (const float*)d_in[4];
  const float* dec_wih = (const float*)d_in[5];
  const float* dec_whh = (const float*)d_in[6];
  const float* dec_bih = (const float*)d_in[7];
  const float* dec_bhh = (const float*)d_in[8];
  const float* w1 = (const float*)d_in[9];
  const float* b1 = (const float*)d_in[10];
  const float* w2 = (const float*)d_in[11];
  const float* b2 = (const float*)d_in[12];
  const int* hor = (const int*)d_in[13];
  float* out = (float*)d_out;
  char* ws = (char*)d_ws;

  split_w<<<dim3(3072), dim3(256), 0, stream>>>(enc_whh, (__bf16*)(ws + OFF_ENH),
                                                (__bf16*)(ws + OFF_ENL), 786432);
  split_w<<<dim3(3072), dim3(256), 0, stream>>>(dec_whh, (__bf16*)(ws + OFF_DEH),
                                                (__bf16*)(ws + OFF_DEL), 786432);
  split_w<<<dim3(1024), dim3(256), 0, stream>>>(w1, (__bf16*)(ws + OFF_W1H),
                                                (__bf16*)(ws + OFF_W1L), 262144);

  // 64 fully-independent WGs (16 batch rows each, all hidden cols local).
  // No inter-WG communication of any kind.
  seq2seq_main<<<dim3(NWG), dim3(NTHR), 0, stream>>>(
      src, enc_wih, enc_bih, enc_bhh, dec_wih, dec_bih, dec_bhh, b1, w2, b2, hor, out, ws);
}

// Round 15
// 58198.071 us; speedup vs baseline: 1.3867x; 1.3867x over previous
//
#include <hip/hip_runtime.h>

typedef __bf16 bf16x8 __attribute__((ext_vector_type(8)));
typedef float f32x4 __attribute__((ext_vector_type(4)));
typedef unsigned u32x4 __attribute__((ext_vector_type(4)));

#define HID 512
#define BATCH 1024
#define SEQL 512
#define NWG 64
#define NTHR 512

// ---- workspace: weight hi/lo planes only (no exchange buffers, no barriers) ----
#define OFF_ENH 0u          // enc_whh hi : 1536*512*2
#define OFF_ENL 1572864u
#define OFF_DEH 3145728u
#define OFF_DEL 4718592u
#define OFF_W1H 6291456u    // w1 hi : 512*512*2
#define OFF_W1L 6815744u
#define WS_NEED 7340032u

// LDS: packed h (bf16 hi | lo<<16) u32 [16][512], XOR-swizzled (32 KB),
// + y-partials [16 rows][8 waves] f32 @32768 (512B) + y[16] @33280 (64B).
#define LDS_PS 32768
#define LDS_Y 33280
#define SWZP(row, cb) (((row) << 11) + ((cb) ^ (((row) & 7) << 4)))

__device__ __forceinline__ f32x4 mfma16(bf16x8 a, bf16x8 b, f32x4 c) {
  return __builtin_amdgcn_mfma_f32_16x16x32_bf16(a, b, c, 0, 0, 0);
}
__device__ __forceinline__ float sig_(float x) { return 1.0f / (1.0f + __expf(-x)); }
__device__ __forceinline__ float tanh_(float x) { return 1.0f - 2.0f / (__expf(2.0f * x) + 1.0f); }

__global__ void split_w(const float* __restrict__ a, __bf16* __restrict__ hi,
                        __bf16* __restrict__ lo, int n) {
  int i = blockIdx.x * blockDim.x + threadIdx.x;
  if (i < n) {
    float v = a[i];
    __bf16 h = (__bf16)v;
    hi[i] = h;
    lo[i] = (__bf16)(v - (float)h);
  }
}

// Read one MFMA A-fragment (16 rows x 32 k, this lane's 8 k-elements) from the
// packed-u32 LDS plane and unpack to hi/lo bf16x8. cb = byte col offset.
__device__ __forceinline__ void rd_afrag(const char* sm, int lan15, int cb, bf16x8& ah,
                                         bf16x8& al) {
  const u32x4 q0 = *(const u32x4*)(sm + SWZP(lan15, cb));
  const u32x4 q1 = *(const u32x4*)(sm + SWZP(lan15, cb + 16));
  u32x4 h, l;
  h.x = (q0.x & 0xffffu) | (q0.y << 16);
  h.y = (q0.z & 0xffffu) | (q0.w << 16);
  h.z = (q1.x & 0xffffu) | (q1.y << 16);
  h.w = (q1.z & 0xffffu) | (q1.w << 16);
  l.x = (q0.x >> 16) | (q0.y & 0xffff0000u);
  l.y = (q0.z >> 16) | (q0.w & 0xffff0000u);
  l.z = (q1.x >> 16) | (q1.y & 0xffff0000u);
  l.w = (q1.z >> 16) | (q1.w & 0xffff0000u);
  ah = __builtin_bit_cast(bf16x8, h);
  al = __builtin_bit_cast(bf16x8, l);
}

// WG = 16 batch rows x ALL 512 hidden cols: the whole recurrence is WG-local.
// 8 waves (2/SIMD); wave wv owns hidden cols [64*wv, 64*wv+64) (4 frags x 3 gates).
// launch_bounds(512, 1): 256-VGPR budget -> the 24-fragment B-batch (96 VGPRs)
// fits in registers and issues as ONE group per kc (r13's 128-cap serialized it;
// r14's 1024-thread variant spilled to scratch -> 43 GB FETCH).
__global__ void __launch_bounds__(NTHR, 1) seq2seq_main(
    const float* __restrict__ src, const float* __restrict__ enc_wih,
    const float* __restrict__ enc_bih, const float* __restrict__ enc_bhh,
    const float* __restrict__ dec_wih, const float* __restrict__ dec_bih,
    const float* __restrict__ dec_bhh, const float* __restrict__ b1,
    const float* __restrict__ w2, const float* __restrict__ b2,
    const int* __restrict__ hor, float* __restrict__ out, char* __restrict__ ws) {
  __shared__ f32x4 smv[2084];  // 33344 B
  char* sm = (char*)smv;
  float* psum = (float*)(sm + LDS_PS);
  float* ylds = (float*)(sm + LDS_Y);

  const __bf16* ench_hi = (const __bf16*)(ws + OFF_ENH);
  const __bf16* ench_lo = (const __bf16*)(ws + OFF_ENL);
  const __bf16* dech_hi = (const __bf16*)(ws + OFF_DEH);
  const __bf16* dech_lo = (const __bf16*)(ws + OFF_DEL);
  const __bf16* w1h = (const __bf16*)(ws + OFF_W1H);
  const __bf16* w1l = (const __bf16*)(ws + OFF_W1L);

  const int G = blockIdx.x;  // rows [16G, 16G+16)
  const int row0 = G << 4;
  const int tid = threadIdx.x;
  const int wv = tid >> 6;  // 0..7
  const int lane = tid & 63;
  const int lan15 = lane & 15;
  const int l4 = lane >> 4;
  const int kbe = l4 << 3;  // A/B k-offset (elements) within 32-chunk

  // B element offsets: gate g, col frag nf -> B row (g*512 + c), c = wv*64+nf*16+lan15
  int boff[3][4];
#pragma unroll
  for (int g = 0; g < 3; ++g)
#pragma unroll
    for (int nf = 0; nf < 4; ++nf)
      boff[g][nf] = (((g << 9) + (wv << 6) + (nf << 4) + lan15) << 9) + kbe;
  int bofffc[4];
#pragma unroll
  for (int nf = 0; nf < 4; ++nf) bofffc[nf] = (((wv << 6) + (nf << 4) + lan15) << 9) + kbe;

  // hoisted encoder gate params (input matmul K=3 inline, f32)
  float wE[3][4][3], biE[3][4], bhE[3][4];
#pragma unroll
  for (int g = 0; g < 3; ++g)
#pragma unroll
    for (int nf = 0; nf < 4; ++nf) {
      const int j = (g << 9) + (wv << 6) + (nf << 4) + lan15;
      wE[g][nf][0] = enc_wih[j * 3 + 0];
      wE[g][nf][1] = enc_wih[j * 3 + 1];
      wE[g][nf][2] = enc_wih[j * 3 + 2];
      biE[g][nf] = enc_bih[j];
      bhE[g][nf] = enc_bhh[j];
    }

  const f32x4 zf = {0.0f, 0.0f, 0.0f, 0.0f};
  float hpv[4][4];  // [nf][reg] f32 carry of h for this lane's 16 outputs
#pragma unroll
  for (int nf = 0; nf < 4; ++nf)
#pragma unroll
    for (int reg = 0; reg < 4; ++reg) hpv[nf][reg] = 0.0f;

  // ================= encoder: 512 steps, fully WG-local =================
  for (int t = 0; t < SEQL; ++t) {
    float xv[4][3];
#pragma unroll
    for (int reg = 0; reg < 4; ++reg) {
      const int grow = row0 + (l4 << 2) + reg;
      const float* xp = src + ((size_t)t * BATCH + grow) * 3;
      xv[reg][0] = xp[0];
      xv[reg][1] = xp[1];
      xv[reg][2] = xp[2];
    }

    f32x4 acc[3][4];
#pragma unroll
    for (int g = 0; g < 3; ++g)
#pragma unroll
      for (int nf = 0; nf < 4; ++nf) acc[g][nf] = zf;

    if (t != 0) {
#pragma unroll 2
      for (int kc = 0; kc < 16; ++kc) {
        const int ko = kc << 5;
        // batch ALL 24 B-loads first: one issue group -> one L2 latency per kc
        bf16x8 bh[3][4], bl[3][4];
#pragma unroll
        for (int g = 0; g < 3; ++g)
#pragma unroll
          for (int nf = 0; nf < 4; ++nf) {
            bh[g][nf] = *(const bf16x8*)(ench_hi + boff[g][nf] + ko);
            bl[g][nf] = *(const bf16x8*)(ench_lo + boff[g][nf] + ko);
          }
        bf16x8 ah, al;
        rd_afrag(sm, lan15, (kc << 7) + (l4 << 5), ah, al);
#pragma unroll
        for (int g = 0; g < 3; ++g)
#pragma unroll
          for (int nf = 0; nf < 4; ++nf) {
            acc[g][nf] = mfma16(ah, bh[g][nf], acc[g][nf]);
            acc[g][nf] = mfma16(al, bh[g][nf], acc[g][nf]);
            acc[g][nf] = mfma16(ah, bl[g][nf], acc[g][nf]);
          }
      }
    }
    __syncthreads();  // all h_t reads done before overwrite

#pragma unroll
    for (int reg = 0; reg < 4; ++reg) {
      const int row = (l4 << 2) + reg;
      const float x0 = xv[reg][0], x1 = xv[reg][1], x2 = xv[reg][2];
#pragma unroll
      for (int nf = 0; nf < 4; ++nf) {
        const float gir =
            fmaf(x0, wE[0][nf][0], fmaf(x1, wE[0][nf][1], fmaf(x2, wE[0][nf][2], biE[0][nf])));
        const float giz =
            fmaf(x0, wE[1][nf][0], fmaf(x1, wE[1][nf][1], fmaf(x2, wE[1][nf][2], biE[1][nf])));
        const float gin =
            fmaf(x0, wE[2][nf][0], fmaf(x1, wE[2][nf][1], fmaf(x2, wE[2][nf][2], biE[2][nf])));
        const float rg = sig_(gir + acc[0][nf][reg] + bhE[0][nf]);
        const float zg = sig_(giz + acc[1][nf][reg] + bhE[1][nf]);
        const float ng = tanh_(gin + rg * (acc[2][nf][reg] + bhE[2][nf]));
        const float hv = fmaf(zg, hpv[nf][reg] - ng, ng);  // (1-z)*n + z*h
        hpv[nf][reg] = hv;
        const __bf16 hb = (__bf16)hv;
        const __bf16 lb = (__bf16)(hv - (float)hb);
        const unsigned pw = (unsigned)__builtin_bit_cast(unsigned short, hb) |
                            ((unsigned)__builtin_bit_cast(unsigned short, lb) << 16);
        const int col = (wv << 6) + (nf << 4) + lan15;
        *(unsigned*)(sm + SWZP(row, col << 2)) = pw;
      }
    }
    __syncthreads();  // h_{t+1} visible to all waves
  }

  // ================= decoder: fully WG-local =================
  float wD[3][4], biD[3][4], bhD[3][4], b1c[4], w2v[4];
#pragma unroll
  for (int g = 0; g < 3; ++g)
#pragma unroll
    for (int nf = 0; nf < 4; ++nf) {
      const int j = (g << 9) + (wv << 6) + (nf << 4) + lan15;
      wD[g][nf] = dec_wih[j];
      biD[g][nf] = dec_bih[j];
      bhD[g][nf] = dec_bhh[j];
    }
#pragma unroll
  for (int nf = 0; nf < 4; ++nf) {
    const int fcol = (wv << 6) + (nf << 4) + lan15;
    b1c[nf] = b1[fcol];
    w2v[nf] = w2[fcol];
  }
  const float b2v = b2[0];
  int H = hor[0];
  if (H < 1 || H > 96) H = 96;

  float facc[4][4];  // fc1 (relu'd, biased) [nf][reg], lives across step boundary

  for (int t = 0; t < H; ++t) {
    // ---- y(t-1) feedback via LDS partial reduce ----
    float din[4];
    if (t == 0) {
#pragma unroll
      for (int reg = 0; reg < 4; ++reg)
        din[reg] = src[((size_t)(SEQL - 1) * BATCH + row0 + (l4 << 2) + reg) * 3];
    } else {
      float ps[4];
#pragma unroll
      for (int reg = 0; reg < 4; ++reg) {
        ps[reg] = facc[0][reg] * w2v[0];
#pragma unroll
        for (int nf = 1; nf < 4; ++nf) ps[reg] = fmaf(facc[nf][reg], w2v[nf], ps[reg]);
#pragma unroll
        for (int off = 1; off < 16; off <<= 1) ps[reg] += __shfl_xor(ps[reg], off, 64);
      }
      if (lan15 == 0) {
#pragma unroll
        for (int reg = 0; reg < 4; ++reg) psum[(((l4 << 2) + reg) << 3) + wv] = ps[reg];
      }
      __syncthreads();
      if (wv == 0 && lane < 16) {
        float s = b2v;
#pragma unroll
        for (int j = 0; j < 8; ++j) s += psum[(lane << 3) + j];
        ylds[lane] = s;
        out[(size_t)(t - 1) * BATCH + row0 + lane] = s;
      }
      __syncthreads();
#pragma unroll
      for (int reg = 0; reg < 4; ++reg) din[reg] = ylds[(l4 << 2) + reg];
    }

    // ---- gates GEMM (h_t from LDS) ----
    f32x4 acc[3][4];
#pragma unroll
    for (int g = 0; g < 3; ++g)
#pragma unroll
      for (int nf = 0; nf < 4; ++nf) acc[g][nf] = zf;
#pragma unroll 2
    for (int kc = 0; kc < 16; ++kc) {
      const int ko = kc << 5;
      bf16x8 bh[3][4], bl[3][4];
#pragma unroll
      for (int g = 0; g < 3; ++g)
#pragma unroll
        for (int nf = 0; nf < 4; ++nf) {
          bh[g][nf] = *(const bf16x8*)(dech_hi + boff[g][nf] + ko);
          bl[g][nf] = *(const bf16x8*)(dech_lo + boff[g][nf] + ko);
        }
      bf16x8 ah, al;
      rd_afrag(sm, lan15, (kc << 7) + (l4 << 5), ah, al);
#pragma unroll
      for (int g = 0; g < 3; ++g)
#pragma unroll
        for (int nf = 0; nf < 4; ++nf) {
          acc[g][nf] = mfma16(ah, bh[g][nf], acc[g][nf]);
          acc[g][nf] = mfma16(al, bh[g][nf], acc[g][nf]);
          acc[g][nf] = mfma16(ah, bl[g][nf], acc[g][nf]);
        }
    }
    __syncthreads();  // all h_t reads done

    // ---- epilogue: h_{t+1} -> LDS ----
#pragma unroll
    for (int reg = 0; reg < 4; ++reg) {
      const int row = (l4 << 2) + reg;
      const float d = din[reg];
#pragma unroll
      for (int nf = 0; nf < 4; ++nf) {
        const float rg = sig_(fmaf(d, wD[0][nf], biD[0][nf]) + acc[0][nf][reg] + bhD[0][nf]);
        const float zg = sig_(fmaf(d, wD[1][nf], biD[1][nf]) + acc[1][nf][reg] + bhD[1][nf]);
        const float ng =
            tanh_(fmaf(d, wD[2][nf], biD[2][nf]) + rg * (acc[2][nf][reg] + bhD[2][nf]));
        const float hv = fmaf(zg, hpv[nf][reg] - ng, ng);
        hpv[nf][reg] = hv;
        const __bf16 hb = (__bf16)hv;
        const __bf16 lb = (__bf16)(hv - (float)hb);
        const unsigned pw = (unsigned)__builtin_bit_cast(unsigned short, hb) |
                            ((unsigned)__builtin_bit_cast(unsigned short, lb) << 16);
        const int col = (wv << 6) + (nf << 4) + lan15;
        *(unsigned*)(sm + SWZP(row, col << 2)) = pw;
      }
    }
    __syncthreads();  // h_{t+1} visible

    // ---- fc1 = relu(h_{t+1} @ w1^T + b1), kept in registers ----
    f32x4 fa[4];
#pragma unroll
    for (int nf = 0; nf < 4; ++nf) fa[nf] = zf;
#pragma unroll 2
    for (int kc = 0; kc < 16; ++kc) {
      const int ko = kc << 5;
      bf16x8 bh[4], bl[4];
#pragma unroll
      for (int nf = 0; nf < 4; ++nf) {
        bh[nf] = *(const bf16x8*)(w1h + bofffc[nf] + ko);
        bl[nf] = *(const bf16x8*)(w1l + bofffc[nf] + ko);
      }
      bf16x8 ah, al;
      rd_afrag(sm, lan15, (kc << 7) + (l4 << 5), ah, al);
#pragma unroll
      for (int nf = 0; nf < 4; ++nf) {
        fa[nf] = mfma16(ah, bh[nf], fa[nf]);
        fa[nf] = mfma16(al, bh[nf], fa[nf]);
        fa[nf] = mfma16(ah, bl[nf], fa[nf]);
      }
    }
#pragma unroll
    for (int nf = 0; nf < 4; ++nf)
#pragma unroll
      for (int reg = 0; reg < 4; ++reg) facc[nf][reg] = fmaxf(fa[nf][reg] + b1c[nf], 0.0f);
  }

  // ---- final y for t = H-1 ----
  {
    float ps[4];
#pragma unroll
    for (int reg = 0; reg < 4; ++reg) {
      ps[reg] = facc[0][reg] * w2v[0];
#pragma unroll
      for (int nf = 1; nf < 4; ++nf) ps[reg] = fmaf(facc[nf][reg], w2v[nf], ps[reg]);
#pragma unroll
      for (int off = 1; off < 16; off <<= 1) ps[reg] += __shfl_xor(ps[reg], off, 64);
    }
    __syncthreads();
    if (lan15 == 0) {
#pragma unroll
      for (int reg = 0; reg < 4; ++reg) psum[(((l4 << 2) + reg) << 3) + wv] = ps[reg];
    }
    __syncthreads();
    if (wv == 0 && lane < 16) {
      float s = b2v;
#pragma unroll
      for (int j = 0; j < 8; ++j) s += psum[(lane << 3) + j];
      out[(size_t)(H - 1) * BATCH + row0 + lane] = s;
    }
  }
}

extern "C" void kernel_launch(void* const* d_in, const int* in_sizes, int n_in,
                              void* d_out, int out_size, void* d_ws, size_t ws_size,
                              hipStream_t stream) {
  if (ws_size < WS_NEED) return;

  const float* src = (const float*)d_in[0];
  const float* enc_wih = (const float*)d_in[1];
  const float* enc_whh = (const float*)d_in[2];
  const float* enc_bih = (const float*)d_in[3];
  const float* enc_bhh = (const float*)d_in[4];
  const float* dec_wih = (const float*)d_in[5];
  const float* dec_whh = (const float*)d_in[6];
  const float* dec_bih = (const float*)d_in[7];
  const float* dec_bhh = (const float*)d_in[8];
  const float* w1 = (const float*)d_in[9];
  const float* b1 = (const float*)d_in[10];
  const float* w2 = (const float*)d_in[11];
  const float* b2 = (const float*)d_in[12];
  const int* hor = (const int*)d_in[13];
  float* out = (float*)d_out;
  char* ws = (char*)d_ws;

  split_w<<<dim3(3072), dim3(256), 0, stream>>>(enc_whh, (__bf16*)(ws + OFF_ENH),
                                                (__bf16*)(ws + OFF_ENL), 786432);
  split_w<<<dim3(3072), dim3(256), 0, stream>>>(dec_whh, (__bf16*)(ws + OFF_DEH),
                                                (__bf16*)(ws + OFF_DEL), 786432);
  split_w<<<dim3(1024), dim3(256), 0, stream>>>(w1, (__bf16*)(ws + OFF_W1H),
                                                (__bf16*)(ws + OFF_W1L), 262144);

  // 64 fully-independent WGs (16 batch rows each, all hidden cols local).
  // No inter-WG communication of any kind.
  seq2seq_main<<<dim3(NWG), dim3(NTHR), 0, stream>>>(
      src, enc_wih, enc_bih, enc_bhh, dec_wih, dec_bih, dec_bhh, b1, w2, b2, hor, out, ws);
}

// Round 16
// 57783.801 us; speedup vs baseline: 1.3966x; 1.0072x over previous
//
#include <hip/hip_runtime.h>

typedef __bf16 bf16x8 __attribute__((ext_vector_type(8)));
typedef float f32x4 __attribute__((ext_vector_type(4)));
typedef unsigned u32x4 __attribute__((ext_vector_type(4)));

#define HID 512
#define BATCH 1024
#define SEQL 512
#define NWG 64
#define NTHR 512

// ---- workspace: weight hi/lo planes only (no exchange buffers, no barriers) ----
#define OFF_ENH 0u          // enc_whh hi : 1536*512*2
#define OFF_ENL 1572864u
#define OFF_DEH 3145728u
#define OFF_DEL 4718592u
#define OFF_W1H 6291456u    // w1 hi : 512*512*2
#define OFF_W1L 6815744u
#define WS_NEED 7340032u

// LDS: packed h (bf16 hi | lo<<16) u32 [16][512], XOR-swizzled (32 KB),
// + y-partials [16 rows][8 waves] f32 @32768 (512B) + y[16] @33280 (64B).
#define LDS_PS 32768
#define LDS_Y 33280
#define SWZP(row, cb) (((row) << 11) + ((cb) ^ (((row) & 7) << 4)))

__device__ __forceinline__ f32x4 mfma16(bf16x8 a, bf16x8 b, f32x4 c) {
  return __builtin_amdgcn_mfma_f32_16x16x32_bf16(a, b, c, 0, 0, 0);
}
__device__ __forceinline__ float sig_(float x) { return 1.0f / (1.0f + __expf(-x)); }
__device__ __forceinline__ float tanh_(float x) { return 1.0f - 2.0f / (__expf(2.0f * x) + 1.0f); }

__global__ void split_w(const float* __restrict__ a, __bf16* __restrict__ hi,
                        __bf16* __restrict__ lo, int n) {
  int i = blockIdx.x * blockDim.x + threadIdx.x;
  if (i < n) {
    float v = a[i];
    __bf16 h = (__bf16)v;
    hi[i] = h;
    lo[i] = (__bf16)(v - (float)h);
  }
}

// Forced-batch B-load: 8 plain cached global_load_dwordx4 issued back-to-back
// in ONE asm block with a single waitcnt. The early-clobber outputs force the
// allocator to provide 32 VGPRs, defeating its load-serializing register reuse
// (r13/r15: ~540 cy/load fully serialized; this pays ONE L2 latency per 8).
// Read-only weight data, plain cached loads -> no memory-model hazard.
__device__ __forceinline__ void ld_b8(const __bf16* __restrict__ Bh,
                                      const __bf16* __restrict__ Bl, const int (&off)[4],
                                      int ko, u32x4 (&d)[8]) {
  const u32x4* p0 = (const u32x4*)(Bh + off[0] + ko);
  const u32x4* p1 = (const u32x4*)(Bh + off[1] + ko);
  const u32x4* p2 = (const u32x4*)(Bh + off[2] + ko);
  const u32x4* p3 = (const u32x4*)(Bh + off[3] + ko);
  const u32x4* p4 = (const u32x4*)(Bl + off[0] + ko);
  const u32x4* p5 = (const u32x4*)(Bl + off[1] + ko);
  const u32x4* p6 = (const u32x4*)(Bl + off[2] + ko);
  const u32x4* p7 = (const u32x4*)(Bl + off[3] + ko);
  asm volatile(
      "global_load_dwordx4 %0, %8, off\n\t"
      "global_load_dwordx4 %1, %9, off\n\t"
      "global_load_dwordx4 %2, %10, off\n\t"
      "global_load_dwordx4 %3, %11, off\n\t"
      "global_load_dwordx4 %4, %12, off\n\t"
      "global_load_dwordx4 %5, %13, off\n\t"
      "global_load_dwordx4 %6, %14, off\n\t"
      "global_load_dwordx4 %7, %15, off\n\t"
      "s_waitcnt vmcnt(0)"
      : "=&v"(d[0]), "=&v"(d[1]), "=&v"(d[2]), "=&v"(d[3]), "=&v"(d[4]), "=&v"(d[5]),
        "=&v"(d[6]), "=&v"(d[7])
      : "v"(p0), "v"(p1), "v"(p2), "v"(p3), "v"(p4), "v"(p5), "v"(p6), "v"(p7));
}

// Read one MFMA A-fragment (16 rows x 32 k, this lane's 8 k-elements) from the
// packed-u32 LDS plane and unpack to hi/lo bf16x8. cb = byte col offset.
__device__ __forceinline__ void rd_afrag(const char* sm, int lan15, int cb, bf16x8& ah,
                                         bf16x8& al) {
  const u32x4 q0 = *(const u32x4*)(sm + SWZP(lan15, cb));
  const u32x4 q1 = *(const u32x4*)(sm + SWZP(lan15, cb + 16));
  u32x4 h, l;
  h.x = (q0.x & 0xffffu) | (q0.y << 16);
  h.y = (q0.z & 0xffffu) | (q0.w << 16);
  h.z = (q1.x & 0xffffu) | (q1.y << 16);
  h.w = (q1.z & 0xffffu) | (q1.w << 16);
  l.x = (q0.x >> 16) | (q0.y & 0xffff0000u);
  l.y = (q0.z >> 16) | (q0.w & 0xffff0000u);
  l.z = (q1.x >> 16) | (q1.y & 0xffff0000u);
  l.w = (q1.z >> 16) | (q1.w & 0xffff0000u);
  ah = __builtin_bit_cast(bf16x8, h);
  al = __builtin_bit_cast(bf16x8, l);
}

// WG = 16 batch rows x ALL 512 hidden cols: the whole recurrence is WG-local.
// 8 waves (2/SIMD); wave wv owns hidden cols [64*wv, 64*wv+64) (4 frags x 3 gates).
__global__ void __launch_bounds__(NTHR, 1) seq2seq_main(
    const float* __restrict__ src, const float* __restrict__ enc_wih,
    const float* __restrict__ enc_bih, const float* __restrict__ enc_bhh,
    const float* __restrict__ dec_wih, const float* __restrict__ dec_bih,
    const float* __restrict__ dec_bhh, const float* __restrict__ b1,
    const float* __restrict__ w2, const float* __restrict__ b2,
    const int* __restrict__ hor, float* __restrict__ out, char* __restrict__ ws) {
  __shared__ f32x4 smv[2084];  // 33344 B
  char* sm = (char*)smv;
  float* psum = (float*)(sm + LDS_PS);
  float* ylds = (float*)(sm + LDS_Y);

  const __bf16* ench_hi = (const __bf16*)(ws + OFF_ENH);
  const __bf16* ench_lo = (const __bf16*)(ws + OFF_ENL);
  const __bf16* dech_hi = (const __bf16*)(ws + OFF_DEH);
  const __bf16* dech_lo = (const __bf16*)(ws + OFF_DEL);
  const __bf16* w1h = (const __bf16*)(ws + OFF_W1H);
  const __bf16* w1l = (const __bf16*)(ws + OFF_W1L);

  const int G = blockIdx.x;  // rows [16G, 16G+16)
  const int row0 = G << 4;
  const int tid = threadIdx.x;
  const int wv = tid >> 6;  // 0..7
  const int lane = tid & 63;
  const int lan15 = lane & 15;
  const int l4 = lane >> 4;
  const int kbe = l4 << 3;  // A/B k-offset (elements) within 32-chunk

  // B element offsets: gate g, col frag nf -> B row (g*512 + c), c = wv*64+nf*16+lan15
  int boff[3][4];
#pragma unroll
  for (int g = 0; g < 3; ++g)
#pragma unroll
    for (int nf = 0; nf < 4; ++nf)
      boff[g][nf] = (((g << 9) + (wv << 6) + (nf << 4) + lan15) << 9) + kbe;
  int bofffc[4];
#pragma unroll
  for (int nf = 0; nf < 4; ++nf) bofffc[nf] = (((wv << 6) + (nf << 4) + lan15) << 9) + kbe;

  // hoisted per-lane encoder gate params (input matmul K=3 inline, f32)
  float wE[3][4][3], biE[3][4], bhE[3][4];
#pragma unroll
  for (int g = 0; g < 3; ++g)
#pragma unroll
    for (int nf = 0; nf < 4; ++nf) {
      const int j = (g << 9) + (wv << 6) + (nf << 4) + lan15;
      wE[g][nf][0] = enc_wih[j * 3 + 0];
      wE[g][nf][1] = enc_wih[j * 3 + 1];
      wE[g][nf][2] = enc_wih[j * 3 + 2];
      biE[g][nf] = enc_bih[j];
      bhE[g][nf] = enc_bhh[j];
    }

  const f32x4 zf = {0.0f, 0.0f, 0.0f, 0.0f};
  float hpv[4][4];  // [nf][reg] f32 carry of h for this lane's 16 outputs
#pragma unroll
  for (int nf = 0; nf < 4; ++nf)
#pragma unroll
    for (int reg = 0; reg < 4; ++reg) hpv[nf][reg] = 0.0f;

  // ================= encoder: 512 steps, fully WG-local =================
  for (int t = 0; t < SEQL; ++t) {
    f32x4 acc[3][4];
#pragma unroll
    for (int g = 0; g < 3; ++g)
#pragma unroll
      for (int nf = 0; nf < 4; ++nf) acc[g][nf] = zf;

    if (t != 0) {
#pragma unroll 2
      for (int kc = 0; kc < 16; ++kc) {
        const int ko = kc << 5;
        bf16x8 ah, al;
        rd_afrag(sm, lan15, (kc << 7) + (l4 << 5), ah, al);
#pragma unroll
        for (int g = 0; g < 3; ++g) {
          u32x4 d[8];
          ld_b8(ench_hi, ench_lo, boff[g], ko, d);
#pragma unroll
          for (int nf = 0; nf < 4; ++nf) {
            const bf16x8 bh = __builtin_bit_cast(bf16x8, d[nf]);
            const bf16x8 bl = __builtin_bit_cast(bf16x8, d[4 + nf]);
            acc[g][nf] = mfma16(ah, bh, acc[g][nf]);
            acc[g][nf] = mfma16(al, bh, acc[g][nf]);
            acc[g][nf] = mfma16(ah, bl, acc[g][nf]);
          }
        }
      }
    }

    // x(t) loaded late (short live range; one batched latency in the epilogue)
    float xv[4][3];
#pragma unroll
    for (int reg = 0; reg < 4; ++reg) {
      const int grow = row0 + (l4 << 2) + reg;
      const float* xp = src + ((size_t)t * BATCH + grow) * 3;
      xv[reg][0] = xp[0];
      xv[reg][1] = xp[1];
      xv[reg][2] = xp[2];
    }
    __syncthreads();  // all h_t reads done before overwrite

#pragma unroll
    for (int reg = 0; reg < 4; ++reg) {
      const int row = (l4 << 2) + reg;
      const float x0 = xv[reg][0], x1 = xv[reg][1], x2 = xv[reg][2];
#pragma unroll
      for (int nf = 0; nf < 4; ++nf) {
        const float gir =
            fmaf(x0, wE[0][nf][0], fmaf(x1, wE[0][nf][1], fmaf(x2, wE[0][nf][2], biE[0][nf])));
        const float giz =
            fmaf(x0, wE[1][nf][0], fmaf(x1, wE[1][nf][1], fmaf(x2, wE[1][nf][2], biE[1][nf])));
        const float gin =
            fmaf(x0, wE[2][nf][0], fmaf(x1, wE[2][nf][1], fmaf(x2, wE[2][nf][2], biE[2][nf])));
        const float rg = sig_(gir + acc[0][nf][reg] + bhE[0][nf]);
        const float zg = sig_(giz + acc[1][nf][reg] + bhE[1][nf]);
        const float ng = tanh_(gin + rg * (acc[2][nf][reg] + bhE[2][nf]));
        const float hv = fmaf(zg, hpv[nf][reg] - ng, ng);  // (1-z)*n + z*h
        hpv[nf][reg] = hv;
        const __bf16 hb = (__bf16)hv;
        const __bf16 lb = (__bf16)(hv - (float)hb);
        const unsigned pw = (unsigned)__builtin_bit_cast(unsigned short, hb) |
                            ((unsigned)__builtin_bit_cast(unsigned short, lb) << 16);
        const int col = (wv << 6) + (nf << 4) + lan15;
        *(unsigned*)(sm + SWZP(row, col << 2)) = pw;
      }
    }
    __syncthreads();  // h_{t+1} visible to all waves
  }

  // ================= decoder: fully WG-local =================
  float wD[3][4], biD[3][4], bhD[3][4], b1c[4], w2v[4];
#pragma unroll
  for (int g = 0; g < 3; ++g)
#pragma unroll
    for (int nf = 0; nf < 4; ++nf) {
      const int j = (g << 9) + (wv << 6) + (nf << 4) + lan15;
      wD[g][nf] = dec_wih[j];
      biD[g][nf] = dec_bih[j];
      bhD[g][nf] = dec_bhh[j];
    }
#pragma unroll
  for (int nf = 0; nf < 4; ++nf) {
    const int fcol = (wv << 6) + (nf << 4) + lan15;
    b1c[nf] = b1[fcol];
    w2v[nf] = w2[fcol];
  }
  const float b2v = b2[0];
  int H = hor[0];
  if (H < 1 || H > 96) H = 96;

  float facc[4][4];  // fc1 (relu'd, biased) [nf][reg], lives across step boundary

  for (int t = 0; t < H; ++t) {
    // ---- y(t-1) feedback via LDS partial reduce ----
    float din[4];
    if (t == 0) {
#pragma unroll
      for (int reg = 0; reg < 4; ++reg)
        din[reg] = src[((size_t)(SEQL - 1) * BATCH + row0 + (l4 << 2) + reg) * 3];
    } else {
      float ps[4];
#pragma unroll
      for (int reg = 0; reg < 4; ++reg) {
        ps[reg] = facc[0][reg] * w2v[0];
#pragma unroll
        for (int nf = 1; nf < 4; ++nf) ps[reg] = fmaf(facc[nf][reg], w2v[nf], ps[reg]);
#pragma unroll
        for (int off = 1; off < 16; off <<= 1) ps[reg] += __shfl_xor(ps[reg], off, 64);
      }
      if (lan15 == 0) {
#pragma unroll
        for (int reg = 0; reg < 4; ++reg) psum[(((l4 << 2) + reg) << 3) + wv] = ps[reg];
      }
      __syncthreads();
      if (wv == 0 && lane < 16) {
        float s = b2v;
#pragma unroll
        for (int j = 0; j < 8; ++j) s += psum[(lane << 3) + j];
        ylds[lane] = s;
        out[(size_t)(t - 1) * BATCH + row0 + lane] = s;
      }
      __syncthreads();
#pragma unroll
      for (int reg = 0; reg < 4; ++reg) din[reg] = ylds[(l4 << 2) + reg];
    }

    // ---- gates GEMM (h_t from LDS) ----
    f32x4 acc[3][4];
#pragma unroll
    for (int g = 0; g < 3; ++g)
#pragma unroll
      for (int nf = 0; nf < 4; ++nf) acc[g][nf] = zf;
#pragma unroll 2
    for (int kc = 0; kc < 16; ++kc) {
      const int ko = kc << 5;
      bf16x8 ah, al;
      rd_afrag(sm, lan15, (kc << 7) + (l4 << 5), ah, al);
#pragma unroll
      for (int g = 0; g < 3; ++g) {
        u32x4 d[8];
        ld_b8(dech_hi, dech_lo, boff[g], ko, d);
#pragma unroll
        for (int nf = 0; nf < 4; ++nf) {
          const bf16x8 bh = __builtin_bit_cast(bf16x8, d[nf]);
          const bf16x8 bl = __builtin_bit_cast(bf16x8, d[4 + nf]);
          acc[g][nf] = mfma16(ah, bh, acc[g][nf]);
          acc[g][nf] = mfma16(al, bh, acc[g][nf]);
          acc[g][nf] = mfma16(ah, bl, acc[g][nf]);
        }
      }
    }
    __syncthreads();  // all h_t reads done

    // ---- epilogue: h_{t+1} -> LDS ----
#pragma unroll
    for (int reg = 0; reg < 4; ++reg) {
      const int row = (l4 << 2) + reg;
      const float d = din[reg];
#pragma unroll
      for (int nf = 0; nf < 4; ++nf) {
        const float rg = sig_(fmaf(d, wD[0][nf], biD[0][nf]) + acc[0][nf][reg] + bhD[0][nf]);
        const float zg = sig_(fmaf(d, wD[1][nf], biD[1][nf]) + acc[1][nf][reg] + bhD[1][nf]);
        const float ng =
            tanh_(fmaf(d, wD[2][nf], biD[2][nf]) + rg * (acc[2][nf][reg] + bhD[2][nf]));
        const float hv = fmaf(zg, hpv[nf][reg] - ng, ng);
        hpv[nf][reg] = hv;
        const __bf16 hb = (__bf16)hv;
        const __bf16 lb = (__bf16)(hv - (float)hb);
        const unsigned pw = (unsigned)__builtin_bit_cast(unsigned short, hb) |
                            ((unsigned)__builtin_bit_cast(unsigned short, lb) << 16);
        const int col = (wv << 6) + (nf << 4) + lan15;
        *(unsigned*)(sm + SWZP(row, col << 2)) = pw;
      }
    }
    __syncthreads();  // h_{t+1} visible

    // ---- fc1 = relu(h_{t+1} @ w1^T + b1), kept in registers ----
    f32x4 fa[4];
#pragma unroll
    for (int nf = 0; nf < 4; ++nf) fa[nf] = zf;
#pragma unroll 2
    for (int kc = 0; kc < 16; ++kc) {
      const int ko = kc << 5;
      bf16x8 ah, al;
      rd_afrag(sm, lan15, (kc << 7) + (l4 << 5), ah, al);
      u32x4 d[8];
      ld_b8(w1h, w1l, bofffc, ko, d);
#pragma unroll
      for (int nf = 0; nf < 4; ++nf) {
        const bf16x8 bh = __builtin_bit_cast(bf16x8, d[nf]);
        const bf16x8 bl = __builtin_bit_cast(bf16x8, d[4 + nf]);
        fa[nf] = mfma16(ah, bh, fa[nf]);
        fa[nf] = mfma16(al, bh, fa[nf]);
        fa[nf] = mfma16(ah, bl, fa[nf]);
      }
    }
#pragma unroll
    for (int nf = 0; nf < 4; ++nf)
#pragma unroll
      for (int reg = 0; reg < 4; ++reg) facc[nf][reg] = fmaxf(fa[nf][reg] + b1c[nf], 0.0f);
  }

  // ---- final y for t = H-1 ----
  {
    float ps[4];
#pragma unroll
    for (int reg = 0; reg < 4; ++reg) {
      ps[reg] = facc[0][reg] * w2v[0];
#pragma unroll
      for (int nf = 1; nf < 4; ++nf) ps[reg] = fmaf(facc[nf][reg], w2v[nf], ps[reg]);
#pragma unroll
      for (int off = 1; off < 16; off <<= 1) ps[reg] += __shfl_xor(ps[reg], off, 64);
    }
    __syncthreads();
    if (lan15 == 0) {
#pragma unroll
      for (int reg = 0; reg < 4; ++reg) psum[(((l4 << 2) + reg) << 3) + wv] = ps[reg];
    }
    __syncthreads();
    if (wv == 0 && lane < 16) {
      float s = b2v;
#pragma unroll
      for (int j = 0; j < 8; ++j) s += psum[(lane << 3) + j];
      out[(size_t)(H - 1) * BATCH + row0 + lane] = s;
    }
  }
}

extern "C" void kernel_launch(void* const* d_in, const int* in_sizes, int n_in,
                              void* d_out, int out_size, void* d_ws, size_t ws_size,
                              hipStream_t stream) {
  if (ws_size < WS_NEED) return;

  const float* src = (const float*)d_in[0];
  const float* enc_wih = (const float*)d_in[1];
  const float* enc_whh = (const float*)d_in[2];
  const float* enc_bih = (const float*)d_in[3];
  const float* enc_bhh = (const float*)d_in[4];
  const float* dec_wih = (const float*)d_in[5];
  const float* dec_whh = (const float*)d_in[6];
  const float* dec_bih = (const float*)d_in[7];
  const float* dec_bhh = (const float*)d_in[8];
  const float* w1 = (const float*)d_in[9];
  const float* b1 = (const float*)d_in[10];
  const float* w2 = (const float*)d_in[11];
  const float* b2 = (const float*)d_in[12];
  const int* hor = (const int*)d_in[13];
  float* out = (float*)d_out;
  char* ws = (char*)d_ws;

  split_w<<<dim3(3072), dim3(256), 0, stream>>>(enc_whh, (__bf16*)(ws + OFF_ENH),
                                                (__bf16*)(ws + OFF_ENL), 786432);
  split_w<<<dim3(3072), dim3(256), 0, stream>>>(dec_whh, (__bf16*)(ws + OFF_DEH),
                                                (__bf16*)(ws + OFF_DEL), 786432);
  split_w<<<dim3(1024), dim3(256), 0, stream>>>(w1, (__bf16*)(ws + OFF_W1H),
                                                (__bf16*)(ws + OFF_W1L), 262144);

  // 64 fully-independent WGs (16 batch rows each, all hidden cols local).
  // No inter-WG communication of any kind.
  seq2seq_main<<<dim3(NWG), dim3(NTHR), 0, stream>>>(
      src, enc_wih, enc_bih, enc_bhh, dec_wih, dec_bih, dec_bhh, b1, w2, b2, hor, out, ws);
}

// Round 17
// 18914.690 us; speedup vs baseline: 4.2666x; 3.0550x over previous
//
#include <hip/hip_runtime.h>

typedef __bf16 bf16x8 __attribute__((ext_vector_type(8)));
typedef float f32x4 __attribute__((ext_vector_type(4)));
typedef unsigned u32x4 __attribute__((ext_vector_type(4)));

#define HID 512
#define BATCH 1024
#define SEQL 512
#define NWG 64
#define NTHR 512

// ---- workspace: fragment-ordered weight hi/lo planes ----
#define OFF_ENH 0u          // enc_whh hi : 786432 bf16
#define OFF_ENL 1572864u
#define OFF_DEH 3145728u
#define OFF_DEL 4718592u
#define OFF_W1H 6291456u    // w1 hi : 262144 bf16
#define OFF_W1L 6815744u
#define WS_NEED 7340032u

// LDS: packed h (bf16 hi | lo<<16) u32 [16][512], XOR-swizzled (32 KB),
// + y-partials [16 rows][8 waves] f32 @32768 (512B) + y[16] @33280 (64B).
#define LDS_PS 32768
#define LDS_Y 33280
#define SWZP(row, cb) (((row) << 11) + ((cb) ^ (((row) & 7) << 4)))

__device__ __forceinline__ f32x4 mfma16(bf16x8 a, bf16x8 b, f32x4 c) {
  return __builtin_amdgcn_mfma_f32_16x16x32_bf16(a, b, c, 0, 0, 0);
}
__device__ __forceinline__ float sig_(float x) { return 1.0f / (1.0f + __expf(-x)); }
__device__ __forceinline__ float tanh_(float x) { return 1.0f - 2.0f / (__expf(2.0f * x) + 1.0f); }

// Split f32 weights into bf16 hi/lo planes laid out in FRAGMENT-SEQUENTIAL
// order: dst[((fi*16 + kc)*64 + lane)*8 + e] = W[colbase(fi)+lan15][kc*32+l4*8+e]
// where colbase(fi) = (fi>>5)*512 + (fi&31)*16, lane = l4*16+lan15.
// In-kernel loads then read base + fi*8192 + kc*512 + lane*8 -> consecutive
// lanes hit consecutive 16B: perfectly coalesced 1KB per instruction (the
// r13-r16 ~540cy/instr scattered-gather cost was the whole bottleneck).
__global__ void split_reorder(const float* __restrict__ a, __bf16* __restrict__ hi,
                              __bf16* __restrict__ lo, int ngrp) {
  const int idx = blockIdx.x * blockDim.x + threadIdx.x;
  if (idx >= ngrp) return;  // ngrp = nfrag*16*64
  const int lane = idx & 63;
  const int kc = (idx >> 6) & 15;
  const int fi = idx >> 10;
  const int lan15 = lane & 15;
  const int l4 = lane >> 4;
  const int col = ((fi >> 5) << 9) + ((fi & 31) << 4) + lan15;
  const int k0 = (kc << 5) + (l4 << 3);
  const float* s = a + (size_t)col * 512 + k0;
  __bf16* dh = hi + (size_t)idx * 8;
  __bf16* dl = lo + (size_t)idx * 8;
#pragma unroll
  for (int e = 0; e < 8; ++e) {
    const float v = s[e];
    const __bf16 h = (__bf16)v;
    dh[e] = h;
    dl[e] = (__bf16)(v - (float)h);
  }
}

// Batched coalesced B-load: 8 x global_load_dwordx4 (4 nf hi + 4 nf lo),
// one waitcnt. Each instr is a contiguous 1KB wave transaction.
__device__ __forceinline__ void ld_b8(const __bf16* __restrict__ Bh,
                                      const __bf16* __restrict__ Bl, const int (&off)[4],
                                      int ko, u32x4 (&d)[8]) {
  const u32x4* p0 = (const u32x4*)(Bh + off[0] + ko);
  const u32x4* p1 = (const u32x4*)(Bh + off[1] + ko);
  const u32x4* p2 = (const u32x4*)(Bh + off[2] + ko);
  const u32x4* p3 = (const u32x4*)(Bh + off[3] + ko);
  const u32x4* p4 = (const u32x4*)(Bl + off[0] + ko);
  const u32x4* p5 = (const u32x4*)(Bl + off[1] + ko);
  const u32x4* p6 = (const u32x4*)(Bl + off[2] + ko);
  const u32x4* p7 = (const u32x4*)(Bl + off[3] + ko);
  asm volatile(
      "global_load_dwordx4 %0, %8, off\n\t"
      "global_load_dwordx4 %1, %9, off\n\t"
      "global_load_dwordx4 %2, %10, off\n\t"
      "global_load_dwordx4 %3, %11, off\n\t"
      "global_load_dwordx4 %4, %12, off\n\t"
      "global_load_dwordx4 %5, %13, off\n\t"
      "global_load_dwordx4 %6, %14, off\n\t"
      "global_load_dwordx4 %7, %15, off\n\t"
      "s_waitcnt vmcnt(0)"
      : "=&v"(d[0]), "=&v"(d[1]), "=&v"(d[2]), "=&v"(d[3]), "=&v"(d[4]), "=&v"(d[5]),
        "=&v"(d[6]), "=&v"(d[7])
      : "v"(p0), "v"(p1), "v"(p2), "v"(p3), "v"(p4), "v"(p5), "v"(p6), "v"(p7));
}

// Read one MFMA A-fragment (16 rows x 32 k, this lane's 8 k-elements) from the
// packed-u32 LDS plane and unpack to hi/lo bf16x8. cb = byte col offset.
__device__ __forceinline__ void rd_afrag(const char* sm, int lan15, int cb, bf16x8& ah,
                                         bf16x8& al) {
  const u32x4 q0 = *(const u32x4*)(sm + SWZP(lan15, cb));
  const u32x4 q1 = *(const u32x4*)(sm + SWZP(lan15, cb + 16));
  u32x4 h, l;
  h.x = (q0.x & 0xffffu) | (q0.y << 16);
  h.y = (q0.z & 0xffffu) | (q0.w << 16);
  h.z = (q1.x & 0xffffu) | (q1.y << 16);
  h.w = (q1.z & 0xffffu) | (q1.w << 16);
  l.x = (q0.x >> 16) | (q0.y & 0xffff0000u);
  l.y = (q0.z >> 16) | (q0.w & 0xffff0000u);
  l.z = (q1.x >> 16) | (q1.y & 0xffff0000u);
  l.w = (q1.z >> 16) | (q1.w & 0xffff0000u);
  ah = __builtin_bit_cast(bf16x8, h);
  al = __builtin_bit_cast(bf16x8, l);
}

// WG = 16 batch rows x ALL 512 hidden cols: the whole recurrence is WG-local.
// 8 waves (2/SIMD); wave wv owns hidden cols [64*wv, 64*wv+64) (4 frags x 3 gates).
__global__ void __launch_bounds__(NTHR, 1) seq2seq_main(
    const float* __restrict__ src, const float* __restrict__ enc_wih,
    const float* __restrict__ enc_bih, const float* __restrict__ enc_bhh,
    const float* __restrict__ dec_wih, const float* __restrict__ dec_bih,
    const float* __restrict__ dec_bhh, const float* __restrict__ b1,
    const float* __restrict__ w2, const float* __restrict__ b2,
    const int* __restrict__ hor, float* __restrict__ out, char* __restrict__ ws) {
  __shared__ f32x4 smv[2084];  // 33344 B
  char* sm = (char*)smv;
  float* psum = (float*)(sm + LDS_PS);
  float* ylds = (float*)(sm + LDS_Y);

  const __bf16* ench_hi = (const __bf16*)(ws + OFF_ENH);
  const __bf16* ench_lo = (const __bf16*)(ws + OFF_ENL);
  const __bf16* dech_hi = (const __bf16*)(ws + OFF_DEH);
  const __bf16* dech_lo = (const __bf16*)(ws + OFF_DEL);
  const __bf16* w1h = (const __bf16*)(ws + OFF_W1H);
  const __bf16* w1l = (const __bf16*)(ws + OFF_W1L);

  const int G = blockIdx.x;  // rows [16G, 16G+16)
  const int row0 = G << 4;
  const int tid = threadIdx.x;
  const int wv = tid >> 6;  // 0..7
  const int lane = tid & 63;
  const int lan15 = lane & 15;
  const int l4 = lane >> 4;

  // Fragment-ordered B offsets: frag fi=(g*32+wv*4+nf) lives at fi*8192,
  // kc stride 512, lane stride 8. COALESCED.
  int boff[3][4];
#pragma unroll
  for (int g = 0; g < 3; ++g)
#pragma unroll
    for (int nf = 0; nf < 4; ++nf)
      boff[g][nf] = (((g << 5) + (wv << 2) + nf) << 13) + (lane << 3);
  int bofffc[4];
#pragma unroll
  for (int nf = 0; nf < 4; ++nf) bofffc[nf] = (((wv << 2) + nf) << 13) + (lane << 3);

  // hoisted per-lane encoder gate params (input matmul K=3 inline, f32)
  float wE[3][4][3], biE[3][4], bhE[3][4];
#pragma unroll
  for (int g = 0; g < 3; ++g)
#pragma unroll
    for (int nf = 0; nf < 4; ++nf) {
      const int j = (g << 9) + (wv << 6) + (nf << 4) + lan15;
      wE[g][nf][0] = enc_wih[j * 3 + 0];
      wE[g][nf][1] = enc_wih[j * 3 + 1];
      wE[g][nf][2] = enc_wih[j * 3 + 2];
      biE[g][nf] = enc_bih[j];
      bhE[g][nf] = enc_bhh[j];
    }

  const f32x4 zf = {0.0f, 0.0f, 0.0f, 0.0f};
  float hpv[4][4];  // [nf][reg] f32 carry of h for this lane's 16 outputs
#pragma unroll
  for (int nf = 0; nf < 4; ++nf)
#pragma unroll
    for (int reg = 0; reg < 4; ++reg) hpv[nf][reg] = 0.0f;

  // ================= encoder: 512 steps, fully WG-local =================
  for (int t = 0; t < SEQL; ++t) {
    f32x4 acc[3][4];
#pragma unroll
    for (int g = 0; g < 3; ++g)
#pragma unroll
      for (int nf = 0; nf < 4; ++nf) acc[g][nf] = zf;

    if (t != 0) {
#pragma unroll 2
      for (int kc = 0; kc < 16; ++kc) {
        const int ko = kc << 9;
        bf16x8 ah, al;
        rd_afrag(sm, lan15, (kc << 7) + (l4 << 5), ah, al);
#pragma unroll
        for (int g = 0; g < 3; ++g) {
          u32x4 d[8];
          ld_b8(ench_hi, ench_lo, boff[g], ko, d);
#pragma unroll
          for (int nf = 0; nf < 4; ++nf) {
            const bf16x8 bh = __builtin_bit_cast(bf16x8, d[nf]);
            const bf16x8 bl = __builtin_bit_cast(bf16x8, d[4 + nf]);
            acc[g][nf] = mfma16(ah, bh, acc[g][nf]);
            acc[g][nf] = mfma16(al, bh, acc[g][nf]);
            acc[g][nf] = mfma16(ah, bl, acc[g][nf]);
          }
        }
      }
    }

    float xv[4][3];
#pragma unroll
    for (int reg = 0; reg < 4; ++reg) {
      const int grow = row0 + (l4 << 2) + reg;
      const float* xp = src + ((size_t)t * BATCH + grow) * 3;
      xv[reg][0] = xp[0];
      xv[reg][1] = xp[1];
      xv[reg][2] = xp[2];
    }
    __syncthreads();  // all h_t reads done before overwrite

#pragma unroll
    for (int reg = 0; reg < 4; ++reg) {
      const int row = (l4 << 2) + reg;
      const float x0 = xv[reg][0], x1 = xv[reg][1], x2 = xv[reg][2];
#pragma unroll
      for (int nf = 0; nf < 4; ++nf) {
        const float gir =
            fmaf(x0, wE[0][nf][0], fmaf(x1, wE[0][nf][1], fmaf(x2, wE[0][nf][2], biE[0][nf])));
        const float giz =
            fmaf(x0, wE[1][nf][0], fmaf(x1, wE[1][nf][1], fmaf(x2, wE[1][nf][2], biE[1][nf])));
        const float gin =
            fmaf(x0, wE[2][nf][0], fmaf(x1, wE[2][nf][1], fmaf(x2, wE[2][nf][2], biE[2][nf])));
        const float rg = sig_(gir + acc[0][nf][reg] + bhE[0][nf]);
        const float zg = sig_(giz + acc[1][nf][reg] + bhE[1][nf]);
        const float ng = tanh_(gin + rg * (acc[2][nf][reg] + bhE[2][nf]));
        const float hv = fmaf(zg, hpv[nf][reg] - ng, ng);  // (1-z)*n + z*h
        hpv[nf][reg] = hv;
        const __bf16 hb = (__bf16)hv;
        const __bf16 lb = (__bf16)(hv - (float)hb);
        const unsigned pw = (unsigned)__builtin_bit_cast(unsigned short, hb) |
                            ((unsigned)__builtin_bit_cast(unsigned short, lb) << 16);
        const int col = (wv << 6) + (nf << 4) + lan15;
        *(unsigned*)(sm + SWZP(row, col << 2)) = pw;
      }
    }
    __syncthreads();  // h_{t+1} visible to all waves
  }

  // ================= decoder: fully WG-local =================
  float wD[3][4], biD[3][4], bhD[3][4], b1c[4], w2v[4];
#pragma unroll
  for (int g = 0; g < 3; ++g)
#pragma unroll
    for (int nf = 0; nf < 4; ++nf) {
      const int j = (g << 9) + (wv << 6) + (nf << 4) + lan15;
      wD[g][nf] = dec_wih[j];
      biD[g][nf] = dec_bih[j];
      bhD[g][nf] = dec_bhh[j];
    }
#pragma unroll
  for (int nf = 0; nf < 4; ++nf) {
    const int fcol = (wv << 6) + (nf << 4) + lan15;
    b1c[nf] = b1[fcol];
    w2v[nf] = w2[fcol];
  }
  const float b2v = b2[0];
  int H = hor[0];
  if (H < 1 || H > 96) H = 96;

  float facc[4][4];  // fc1 (relu'd, biased) [nf][reg], lives across step boundary

  for (int t = 0; t < H; ++t) {
    // ---- y(t-1) feedback via LDS partial reduce ----
    float din[4];
    if (t == 0) {
#pragma unroll
      for (int reg = 0; reg < 4; ++reg)
        din[reg] = src[((size_t)(SEQL - 1) * BATCH + row0 + (l4 << 2) + reg) * 3];
    } else {
      float ps[4];
#pragma unroll
      for (int reg = 0; reg < 4; ++reg) {
        ps[reg] = facc[0][reg] * w2v[0];
#pragma unroll
        for (int nf = 1; nf < 4; ++nf) ps[reg] = fmaf(facc[nf][reg], w2v[nf], ps[reg]);
#pragma unroll
        for (int off = 1; off < 16; off <<= 1) ps[reg] += __shfl_xor(ps[reg], off, 64);
      }
      if (lan15 == 0) {
#pragma unroll
        for (int reg = 0; reg < 4; ++reg) psum[(((l4 << 2) + reg) << 3) + wv] = ps[reg];
      }
      __syncthreads();
      if (wv == 0 && lane < 16) {
        float s = b2v;
#pragma unroll
        for (int j = 0; j < 8; ++j) s += psum[(lane << 3) + j];
        ylds[lane] = s;
        out[(size_t)(t - 1) * BATCH + row0 + lane] = s;
      }
      __syncthreads();
#pragma unroll
      for (int reg = 0; reg < 4; ++reg) din[reg] = ylds[(l4 << 2) + reg];
    }

    // ---- gates GEMM (h_t from LDS) ----
    f32x4 acc[3][4];
#pragma unroll
    for (int g = 0; g < 3; ++g)
#pragma unroll
      for (int nf = 0; nf < 4; ++nf) acc[g][nf] = zf;
#pragma unroll 2
    for (int kc = 0; kc < 16; ++kc) {
      const int ko = kc << 9;
      bf16x8 ah, al;
      rd_afrag(sm, lan15, (kc << 7) + (l4 << 5), ah, al);
#pragma unroll
      for (int g = 0; g < 3; ++g) {
        u32x4 d[8];
        ld_b8(dech_hi, dech_lo, boff[g], ko, d);
#pragma unroll
        for (int nf = 0; nf < 4; ++nf) {
          const bf16x8 bh = __builtin_bit_cast(bf16x8, d[nf]);
          const bf16x8 bl = __builtin_bit_cast(bf16x8, d[4 + nf]);
          acc[g][nf] = mfma16(ah, bh, acc[g][nf]);
          acc[g][nf] = mfma16(al, bh, acc[g][nf]);
          acc[g][nf] = mfma16(ah, bl, acc[g][nf]);
        }
      }
    }
    __syncthreads();  // all h_t reads done

    // ---- epilogue: h_{t+1} -> LDS ----
#pragma unroll
    for (int reg = 0; reg < 4; ++reg) {
      const int row = (l4 << 2) + reg;
      const float d = din[reg];
#pragma unroll
      for (int nf = 0; nf < 4; ++nf) {
        const float rg = sig_(fmaf(d, wD[0][nf], biD[0][nf]) + acc[0][nf][reg] + bhD[0][nf]);
        const float zg = sig_(fmaf(d, wD[1][nf], biD[1][nf]) + acc[1][nf][reg] + bhD[1][nf]);
        const float ng =
            tanh_(fmaf(d, wD[2][nf], biD[2][nf]) + rg * (acc[2][nf][reg] + bhD[2][nf]));
        const float hv = fmaf(zg, hpv[nf][reg] - ng, ng);
        hpv[nf][reg] = hv;
        const __bf16 hb = (__bf16)hv;
        const __bf16 lb = (__bf16)(hv - (float)hb);
        const unsigned pw = (unsigned)__builtin_bit_cast(unsigned short, hb) |
                            ((unsigned)__builtin_bit_cast(unsigned short, lb) << 16);
        const int col = (wv << 6) + (nf << 4) + lan15;
        *(unsigned*)(sm + SWZP(row, col << 2)) = pw;
      }
    }
    __syncthreads();  // h_{t+1} visible

    // ---- fc1 = relu(h_{t+1} @ w1^T + b1), kept in registers ----
    f32x4 fa[4];
#pragma unroll
    for (int nf = 0; nf < 4; ++nf) fa[nf] = zf;
#pragma unroll 2
    for (int kc = 0; kc < 16; ++kc) {
      const int ko = kc << 9;
      bf16x8 ah, al;
      rd_afrag(sm, lan15, (kc << 7) + (l4 << 5), ah, al);
      u32x4 d[8];
      ld_b8(w1h, w1l, bofffc, ko, d);
#pragma unroll
      for (int nf = 0; nf < 4; ++nf) {
        const bf16x8 bh = __builtin_bit_cast(bf16x8, d[nf]);
        const bf16x8 bl = __builtin_bit_cast(bf16x8, d[4 + nf]);
        fa[nf] = mfma16(ah, bh, fa[nf]);
        fa[nf] = mfma16(al, bh, fa[nf]);
        fa[nf] = mfma16(ah, bl, fa[nf]);
      }
    }
#pragma unroll
    for (int nf = 0; nf < 4; ++nf)
#pragma unroll
      for (int reg = 0; reg < 4; ++reg) facc[nf][reg] = fmaxf(fa[nf][reg] + b1c[nf], 0.0f);
  }

  // ---- final y for t = H-1 ----
  {
    float ps[4];
#pragma unroll
    for (int reg = 0; reg < 4; ++reg) {
      ps[reg] = facc[0][reg] * w2v[0];
#pragma unroll
      for (int nf = 1; nf < 4; ++nf) ps[reg] = fmaf(facc[nf][reg], w2v[nf], ps[reg]);
#pragma unroll
      for (int off = 1; off < 16; off <<= 1) ps[reg] += __shfl_xor(ps[reg], off, 64);
    }
    __syncthreads();
    if (lan15 == 0) {
#pragma unroll
      for (int reg = 0; reg < 4; ++reg) psum[(((l4 << 2) + reg) << 3) + wv] = ps[reg];
    }
    __syncthreads();
    if (wv == 0 && lane < 16) {
      float s = b2v;
#pragma unroll
      for (int j = 0; j < 8; ++j) s += psum[(lane << 3) + j];
      out[(size_t)(H - 1) * BATCH + row0 + lane] = s;
    }
  }
}

extern "C" void kernel_launch(void* const* d_in, const int* in_sizes, int n_in,
                              void* d_out, int out_size, void* d_ws, size_t ws_size,
                              hipStream_t stream) {
  if (ws_size < WS_NEED) return;

  const float* src = (const float*)d_in[0];
  const float* enc_wih = (const float*)d_in[1];
  const float* enc_whh = (const float*)d_in[2];
  const float* enc_bih = (const float*)d_in[3];
  const float* enc_bhh = (const float*)d_in[4];
  const float* dec_wih = (const float*)d_in[5];
  const float* dec_whh = (const float*)d_in[6];
  const float* dec_bih = (const float*)d_in[7];
  const float* dec_bhh = (const float*)d_in[8];
  const float* w1 = (const float*)d_in[9];
  const float* b1 = (const float*)d_in[10];
  const float* w2 = (const float*)d_in[11];
  const float* b2 = (const float*)d_in[12];
  const int* hor = (const int*)d_in[13];
  float* out = (float*)d_out;
  char* ws = (char*)d_ws;

  // fragment-sequential reorder+split (96 frags for whh, 32 for w1)
  split_reorder<<<dim3(384), dim3(256), 0, stream>>>(
      enc_whh, (__bf16*)(ws + OFF_ENH), (__bf16*)(ws + OFF_ENL), 98304);
  split_reorder<<<dim3(384), dim3(256), 0, stream>>>(
      dec_whh, (__bf16*)(ws + OFF_DEH), (__bf16*)(ws + OFF_DEL), 98304);
  split_reorder<<<dim3(128), dim3(256), 0, stream>>>(
      w1, (__bf16*)(ws + OFF_W1H), (__bf16*)(ws + OFF_W1L), 32768);

  // 64 fully-independent WGs (16 batch rows each, all hidden cols local).
  seq2seq_main<<<dim3(NWG), dim3(NTHR), 0, stream>>>(
      src, enc_wih, enc_bih, enc_bhh, dec_wih, dec_bih, dec_bhh, b1, w2, b2, hor, out, ws);
}